// Round 8
// baseline (204.676 us; speedup 1.0000x reference)
//
#include <hip/hip_runtime.h>
#include <hip/hip_bf16.h>

typedef __attribute__((ext_vector_type(8))) short bf16x8;
typedef __attribute__((ext_vector_type(4))) float f32x4;
typedef __attribute__((ext_vector_type(4))) unsigned short u16x4;
typedef __attribute__((ext_vector_type(4))) unsigned int u32x4;
typedef __attribute__((ext_vector_type(2))) unsigned int u32x2;

#define MFMA16(a, b, c) __builtin_amdgcn_mfma_f32_16x16x32_bf16((a), (b), (c), 0, 0, 0)

#define WQT_ELEMS 27648   // 288*96
#define WPT_ELEMS 9216    // 96*96

__device__ __forceinline__ unsigned short cvt_bf(float f) {
    __hip_bfloat16 h = __float2bfloat16(f);   // native RNE conversion
    return *reinterpret_cast<unsigned short*>(&h);
}
__device__ __forceinline__ unsigned pack2bf(float a, float b) {
    return (unsigned)cvt_bf(a) | ((unsigned)cvt_bf(b) << 16);
}

// Transpose+convert weights; q-columns (j<96) pre-scaled by (1/sqrt(24))*log2(e)
__global__ void wconv_kernel(const float* __restrict__ wqkv,
                             const float* __restrict__ wproj,
                             unsigned short* __restrict__ wsT) {
    int o = blockIdx.x * 256 + threadIdx.x;
    if (o < WQT_ELEMS) {
        int j = o / 96, c = o % 96;
        float w = wqkv[c * 288 + j];
        if (j < 96) w *= 0.2944889313f;
        wsT[o] = cvt_bf(w);
    } else if (o < WQT_ELEMS + WPT_ELEMS) {
        int o2 = o - WQT_ELEMS;
        int j = o2 / 96, c = o2 % 96;
        wsT[o] = cvt_bf(wproj[c * 96 + j]);
    }
}

// Packed-swizzled address (t in [0,64), c in [0,96)): 3 chunks of 32 cols;
// 2 token-rows per 128B line; XOR swizzle on bits 4-6.
__device__ __forceinline__ int xq_addr(int t, int c) {
    return ((c >> 5) << 12) + ((t >> 1) << 7)
         + ((((t & 1) << 6) + ((c & 31) << 1)) ^ (((t >> 1) & 7) << 4));
}

// One block per window. 256 threads = 4 waves. Wave wv owns token rows [16wv,16wv+16).
// LDS = 53248 B -> 3 blocks/CU (the real cap observed at 40960 anyway).
// x (XQ) is IMMUTABLE through phase 2: QKV runs as two token-half passes with
// afr[2][3] (24 VGPR) instead of afr[4][3] (48) -> no spill pressure at any point.
__global__ __launch_bounds__(256, 3)
void winattn_kernel(const float* __restrict__ x,
                    const unsigned short* __restrict__ wsT,
                    const float* __restrict__ bproj,
                    float* __restrict__ out) {
    __shared__ __align__(16) char XQ[12288];   // x (phases 1-2), then O (phases 3-4, wave-own rows)
    __shared__ __align__(16) char QK[28672];   // q [0,12288) + k [12288,28672); fbuf overlays [0,25600)
    __shared__ __align__(16) char VT[12288];   // v^T [ch][tok], XOR-swizzled
    char* qb  = QK;
    char* ksb = QK + 12288;
    char* vtb = VT;
    float* fbuf = reinterpret_cast<float*>(QK);

    const int tid = threadIdx.x;
    const int lane = tid & 63;
    const int wv = tid >> 6;
    const int p  = lane & 15;
    const int qg = lane >> 4;

    const int iw  = blockIdx.x;
    const int l_i = iw & 31;
    const int m_i = (iw >> 5) & 15;
    const int n_i = iw >> 9;

    const f32x4 fzero = {0.f, 0.f, 0.f, 0.f};

    // ---------- phase 1: stage x window -> LDS (bf16, packed layout) ----------
    #pragma unroll
    for (int it = 0; it < 6; ++it) {
        int slot = tid + it * 256;            // 64 tokens * 24 float4 slots
        int t = slot / 24, cq = slot % 24;
        int td = t >> 4, th = (t >> 2) & 3, tw = t & 3;
        int off = (((n_i * 4 + td) * 64 + (m_i * 4 + th)) * 128 + (l_i * 4 + tw)) * 96 + cq * 4;
        float4 v4 = *reinterpret_cast<const float4*>(x + off);
        u16x4 h;
        h[0] = cvt_bf(v4.x); h[1] = cvt_bf(v4.y); h[2] = cvt_bf(v4.z); h[3] = cvt_bf(v4.w);
        *reinterpret_cast<u16x4*>(XQ + xq_addr(t, cq * 4)) = h;
    }
    // zero k head-pads (kk 24..31 per head, swizzled addr)
    {
        int t = tid >> 2, hd = tid & 3;
        bf16x8 z = {0, 0, 0, 0, 0, 0, 0, 0};
        int cb = hd * 64 + 48;
        *reinterpret_cast<bf16x8*>(ksb + t * 256 + (cb ^ ((t & 7) << 4))) = z;
    }
    __syncthreads();

    // ---------- phase 2: QKV GEMM (swapped), two token-half passes ----------
    auto load_w = [&](int m, bf16x8* wc) {
        #pragma unroll
        for (int kt = 0; kt < 3; ++kt)
            wc[kt] = *reinterpret_cast<const bf16x8*>(&wsT[(m * 16 + p) * 96 + kt * 32 + qg * 8]);
    };

    #pragma unroll
    for (int h = 0; h < 2; ++h) {
        bf16x8 a2[2][3];                       // x fragments for tokens [h*32, h*32+32)
        #pragma unroll
        for (int j = 0; j < 2; ++j)
            #pragma unroll
            for (int kt = 0; kt < 3; ++kt)
                a2[j][kt] = *reinterpret_cast<const bf16x8*>(XQ + xq_addr((h * 2 + j) * 16 + p, kt * 32 + qg * 8));

        auto doQ = [&](int m, const bf16x8* wc) {
            f32x4 acc[2] = {fzero, fzero};
            #pragma unroll
            for (int kt = 0; kt < 3; ++kt)
                #pragma unroll
                for (int j = 0; j < 2; ++j)
                    acc[j] = MFMA16(wc[kt], a2[j][kt], acc[j]);
            int ch = m * 16 + 4 * qg;
            #pragma unroll
            for (int j = 0; j < 2; ++j) {
                u32x2 w = { pack2bf(acc[j][0], acc[j][1]), pack2bf(acc[j][2], acc[j][3]) };
                *reinterpret_cast<u32x2*>(qb + xq_addr((h * 2 + j) * 16 + p, ch)) = w;
            }
        };
        auto doK = [&](int m, const bf16x8* wc) {
            f32x4 acc[2] = {fzero, fzero};
            #pragma unroll
            for (int kt = 0; kt < 3; ++kt)
                #pragma unroll
                for (int j = 0; j < 2; ++j)
                    acc[j] = MFMA16(wc[kt], a2[j][kt], acc[j]);
            int jk = (m - 6) * 16 + 4 * qg;    // 4-run stays within one head
            int cb = jk * 2 + (jk / 24) * 16;
            #pragma unroll
            for (int j = 0; j < 2; ++j) {
                int t = (h * 2 + j) * 16 + p;
                u32x2 w = { pack2bf(acc[j][0], acc[j][1]), pack2bf(acc[j][2], acc[j][3]) };
                *reinterpret_cast<u32x2*>(ksb + t * 256 + (cb ^ ((t & 7) << 4))) = w;
            }
        };
        auto doV = [&](int m, const bf16x8* wc) {
            f32x4 acc[2] = {fzero, fzero};
            #pragma unroll
            for (int kt = 0; kt < 3; ++kt)
                #pragma unroll
                for (int j = 0; j < 2; ++j)
                    acc[j] = MFMA16(wc[kt], a2[j][kt], acc[j]);
            int jv = (m - 12) * 16 + 4 * qg;
            #pragma unroll
            for (int j = 0; j < 2; ++j) {
                int t2 = ((h * 2 + j) * 16 + p) * 2;
                #pragma unroll
                for (int rg = 0; rg < 4; ++rg) {
                    int row = jv + rg;
                    *reinterpret_cast<unsigned short*>(vtb + row * 128 + (t2 ^ ((row & 7) << 4))) = cvt_bf(acc[j][rg]);
                }
            }
        };

        bf16x8 wA[3], wB[3];
        if (wv == 0) {          // tiles 0-4: all q
            load_w(0, wA);
            load_w(1, wB); doQ(0, wA);
            load_w(2, wA); doQ(1, wB);
            load_w(3, wB); doQ(2, wA);
            load_w(4, wA); doQ(3, wB);
            doQ(4, wA);
        } else if (wv == 1) {   // tiles 5-9: q, then k
            load_w(5, wA);
            load_w(6, wB); doQ(5, wA);
            load_w(7, wA); doK(6, wB);
            load_w(8, wB); doK(7, wA);
            load_w(9, wA); doK(8, wB);
            doK(9, wA);
        } else if (wv == 2) {   // tiles 10-13: k, k, v, v
            load_w(10, wA);
            load_w(11, wB); doK(10, wA);
            load_w(12, wA); doK(11, wB);
            load_w(13, wB); doV(12, wA);
            doV(13, wB);
        } else {                // tiles 14-17: all v
            load_w(14, wA);
            load_w(15, wB); doV(14, wA);
            load_w(16, wA); doV(15, wB);
            load_w(17, wB); doV(16, wA);
            doV(17, wB);
        }
    }
    __syncthreads();

    // ---------- phase 3: attention, swapped QK^T -> register softmax -> swapped PV ----------
    #pragma unroll 1
    for (int hd = 0; hd < 4; ++hd) {
        // S^T = mfma(K, Q): D[col=q-token(p), row=k-token(qg*4+rg)+16nt]
        bf16x8 aqh = *reinterpret_cast<const bf16x8*>(qb + xq_addr(wv * 16 + p, hd * 24 + qg * 8));
        f32x4 sacc[4];
        #pragma unroll
        for (int nt = 0; nt < 4; ++nt) {
            int t = nt * 16 + p;
            bf16x8 ak = *reinterpret_cast<const bf16x8*>(ksb + t * 256 + ((hd * 64 + qg * 16) ^ ((t & 7) << 4)));
            sacc[nt] = MFMA16(ak, aqh, fzero);
        }
        // lane (p,qg) holds S[k = 16nt+4qg+rg][q = wv*16+p] (already *scale*log2e)
        float mm = sacc[0][0];
        #pragma unroll
        for (int nt = 0; nt < 4; ++nt)
            #pragma unroll
            for (int rg = 0; rg < 4; ++rg)
                mm = fmaxf(mm, sacc[nt][rg]);
        mm = fmaxf(mm, __shfl_xor(mm, 16));
        mm = fmaxf(mm, __shfl_xor(mm, 32));
        float pw[4][4];
        float sum = 0.f;
        #pragma unroll
        for (int nt = 0; nt < 4; ++nt)
            #pragma unroll
            for (int rg = 0; rg < 4; ++rg) {
                float e = exp2f(sacc[nt][rg] - mm);
                pw[nt][rg] = e;
                sum += e;
            }
        sum += __shfl_xor(sum, 16);
        sum += __shfl_xor(sum, 32);
        float inv = 1.0f / sum;
        unsigned pk[4][2];
        #pragma unroll
        for (int nt = 0; nt < 4; ++nt) {
            pk[nt][0] = pack2bf(pw[nt][0] * inv, pw[nt][1] * inv);
            pk[nt][1] = pack2bf(pw[nt][2] * inv, pw[nt][3] * inv);
        }
        // redistribute so lane (p,qg) holds P[qtok=p][ktok = kt*32 + qg*8 + j]
        u32x4 pa0, pa1;
        #pragma unroll
        for (int d = 0; d < 4; ++d) {
            int src = ((qg & 1) * 2 + (d >> 1)) * 16 + p;
            int lo0 = __shfl((int)pk[0][d & 1], src);
            int hi0 = __shfl((int)pk[1][d & 1], src);
            int lo1 = __shfl((int)pk[2][d & 1], src);
            int hi1 = __shfl((int)pk[3][d & 1], src);
            pa0[d] = (qg < 2) ? (unsigned)lo0 : (unsigned)hi0;
            pa1[d] = (qg < 2) ? (unsigned)lo1 : (unsigned)hi1;
        }
        bf16x8 a0 = __builtin_bit_cast(bf16x8, pa0);
        bf16x8 a1 = __builtin_bit_cast(bf16x8, pa1);
        // O^T = mfma(V^T, P^T)
        f32x4 oacc[2] = {fzero, fzero};
        #pragma unroll
        for (int n2 = 0; n2 < 2; ++n2) {
            int vr = hd * 24 + n2 * 16 + p;
            vr = vr > 95 ? 95 : vr;           // clamped garbage rows land in discarded D rows
            int rb = vr * 128, sw = (vr & 7) << 4;
            bf16x8 av0 = *reinterpret_cast<const bf16x8*>(vtb + rb + ((qg * 16) ^ sw));
            bf16x8 av1 = *reinterpret_cast<const bf16x8*>(vtb + rb + ((64 + qg * 16) ^ sw));
            oacc[n2] = MFMA16(av0, a0, oacc[n2]);
            oacc[n2] = MFMA16(av1, a1, oacc[n2]);
        }
        // lane holds O[tok = wv*16+p][ch = hd*24 + n2*16 + 4qg + rg] -> b64 stores into XQ
        {
            u32x2 w0 = { pack2bf(oacc[0][0], oacc[0][1]), pack2bf(oacc[0][2], oacc[0][3]) };
            *reinterpret_cast<u32x2*>(XQ + xq_addr(wv * 16 + p, hd * 24 + 4 * qg)) = w0;
            if (qg < 2) {
                u32x2 w1 = { pack2bf(oacc[1][0], oacc[1][1]), pack2bf(oacc[1][2], oacc[1][3]) };
                *reinterpret_cast<u32x2*>(XQ + xq_addr(wv * 16 + p, hd * 24 + 16 + 4 * qg)) = w1;
            }
        }
    }

    // ---------- phase 4: proj (swapped) + bias -> f32 LDS (own rows only) ----------
    bf16x8 ofr[3];
    #pragma unroll
    for (int kt = 0; kt < 3; ++kt)
        ofr[kt] = *reinterpret_cast<const bf16x8*>(XQ + xq_addr(wv * 16 + p, kt * 32 + qg * 8));
    __syncthreads();   // all waves done with qb/ksb before fbuf overlays them

    const unsigned short* wpT = wsT + WQT_ELEMS;
    bf16x8 wpre[3];
    #pragma unroll
    for (int kt = 0; kt < 3; ++kt)
        wpre[kt] = *reinterpret_cast<const bf16x8*>(&wpT[p * 96 + kt * 32 + qg * 8]);
    #pragma unroll
    for (int m = 0; m < 6; ++m) {
        bf16x8 wcur[3] = {wpre[0], wpre[1], wpre[2]};
        if (m < 5) {
            #pragma unroll
            for (int kt = 0; kt < 3; ++kt)
                wpre[kt] = *reinterpret_cast<const bf16x8*>(&wpT[((m + 1) * 16 + p) * 96 + kt * 32 + qg * 8]);
        }
        f32x4 acc = fzero;
        #pragma unroll
        for (int kt = 0; kt < 3; ++kt)
            acc = MFMA16(wcur[kt], ofr[kt], acc);
        // lane holds out[tok = wv*16+p][ch = m*16 + 4qg + rg]
        float4 bb = *reinterpret_cast<const float4*>(bproj + m * 16 + 4 * qg);
        f32x4 r;
        r[0] = acc[0] + bb.x; r[1] = acc[1] + bb.y;
        r[2] = acc[2] + bb.z; r[3] = acc[3] + bb.w;
        *reinterpret_cast<f32x4*>(fbuf + (wv * 16 + p) * 100 + m * 16 + 4 * qg) = r;
    }
    __syncthreads();

    // ---------- phase 5: cooperative fully-coalesced f32 store ----------
    #pragma unroll
    for (int it = 0; it < 6; ++it) {
        int slot = tid + it * 256;
        int t = slot / 24, cq = slot % 24;
        int td = t >> 4, th = (t >> 2) & 3, tw = t & 3;
        int off = (((n_i * 4 + td) * 64 + (m_i * 4 + th)) * 128 + (l_i * 4 + tw)) * 96 + cq * 4;
        float4 v4 = *reinterpret_cast<const float4*>(fbuf + t * 100 + cq * 4);
        *reinterpret_cast<float4*>(out + off) = v4;
    }
}

extern "C" void kernel_launch(void* const* d_in, const int* in_sizes, int n_in,
                              void* d_out, int out_size, void* d_ws, size_t ws_size,
                              hipStream_t stream) {
    const float* x     = (const float*)d_in[0];
    const float* wqkv  = (const float*)d_in[1];
    const float* wproj = (const float*)d_in[2];
    const float* bproj = (const float*)d_in[3];
    float* out = (float*)d_out;
    unsigned short* wsT = (unsigned short*)d_ws;

    wconv_kernel<<<dim3((WQT_ELEMS + WPT_ELEMS) / 256), dim3(256), 0, stream>>>(wqkv, wproj, wsT);
    winattn_kernel<<<dim3(4096), dim3(256), 0, stream>>>(x, wsT, bproj, out);
}

// Round 9
// 80.159 us; speedup vs baseline: 2.5534x; 2.5534x over previous
//
#include <hip/hip_runtime.h>
#include <hip/hip_bf16.h>

typedef __attribute__((ext_vector_type(8))) short bf16x8;
typedef __attribute__((ext_vector_type(4))) float f32x4;
typedef __attribute__((ext_vector_type(4))) unsigned short u16x4;
typedef __attribute__((ext_vector_type(4))) unsigned int u32x4;
typedef __attribute__((ext_vector_type(2))) unsigned int u32x2;

#define MFMA16(a, b, c) __builtin_amdgcn_mfma_f32_16x16x32_bf16((a), (b), (c), 0, 0, 0)

#define WQT_ELEMS 27648   // 288*96
#define WPT_ELEMS 9216    // 96*96

__device__ __forceinline__ unsigned short cvt_bf(float f) {
    __hip_bfloat16 h = __float2bfloat16(f);   // native RNE conversion
    return *reinterpret_cast<unsigned short*>(&h);
}
__device__ __forceinline__ unsigned pack2bf(float a, float b) {
    return (unsigned)cvt_bf(a) | ((unsigned)cvt_bf(b) << 16);
}

// Transpose+convert weights; q-columns (j<96) pre-scaled by (1/sqrt(24))*log2(e)
__global__ void wconv_kernel(const float* __restrict__ wqkv,
                             const float* __restrict__ wproj,
                             unsigned short* __restrict__ wsT) {
    int o = blockIdx.x * 256 + threadIdx.x;
    if (o < WQT_ELEMS) {
        int j = o / 96, c = o % 96;
        float w = wqkv[c * 288 + j];
        if (j < 96) w *= 0.2944889313f;
        wsT[o] = cvt_bf(w);
    } else if (o < WQT_ELEMS + WPT_ELEMS) {
        int o2 = o - WQT_ELEMS;
        int j = o2 / 96, c = o2 % 96;
        wsT[o] = cvt_bf(wproj[c * 96 + j]);
    }
}

// Packed-swizzled address (t in [0,64), c in [0,96)): 3 chunks of 32 cols;
// 2 token-rows per 128B line; XOR swizzle on bits 4-6.
__device__ __forceinline__ int xq_addr(int t, int c) {
    return ((c >> 5) << 12) + ((t >> 1) << 7)
         + ((((t & 1) << 6) + ((c & 31) << 1)) ^ (((t >> 1) & 7) << 4));
}

// ---- scratch-proof fragment movement: named scalars only, via macros ----
#define LOADW(m, W0, W1, W2) do {                                              \
    const unsigned short* _wp = wsT + ((m) * 16 + p) * 96 + qg * 8;            \
    W0 = *reinterpret_cast<const bf16x8*>(_wp);                                \
    W1 = *reinterpret_cast<const bf16x8*>(_wp + 32);                           \
    W2 = *reinterpret_cast<const bf16x8*>(_wp + 64);                           \
} while (0)

#define MFMA_T(W0, W1, W2)                                                     \
    f32x4 ac0 = fzero, ac1 = fzero, ac2 = fzero, ac3 = fzero;                  \
    ac0 = MFMA16(W0, a00, ac0); ac1 = MFMA16(W0, a10, ac1);                    \
    ac2 = MFMA16(W0, a20, ac2); ac3 = MFMA16(W0, a30, ac3);                    \
    ac0 = MFMA16(W1, a01, ac0); ac1 = MFMA16(W1, a11, ac1);                    \
    ac2 = MFMA16(W1, a21, ac2); ac3 = MFMA16(W1, a31, ac3);                    \
    ac0 = MFMA16(W2, a02, ac0); ac1 = MFMA16(W2, a12, ac1);                    \
    ac2 = MFMA16(W2, a22, ac2); ac3 = MFMA16(W2, a32, ac3);

#define DO_Q(m, W0, W1, W2) do {                                               \
    MFMA_T(W0, W1, W2)                                                         \
    int ch = (m) * 16 + 4 * qg;                                                \
    *reinterpret_cast<u32x2*>(xq + xq_addr(p,      ch)) = (u32x2){pack2bf(ac0[0],ac0[1]), pack2bf(ac0[2],ac0[3])}; \
    *reinterpret_cast<u32x2*>(xq + xq_addr(16 + p, ch)) = (u32x2){pack2bf(ac1[0],ac1[1]), pack2bf(ac1[2],ac1[3])}; \
    *reinterpret_cast<u32x2*>(xq + xq_addr(32 + p, ch)) = (u32x2){pack2bf(ac2[0],ac2[1]), pack2bf(ac2[2],ac2[3])}; \
    *reinterpret_cast<u32x2*>(xq + xq_addr(48 + p, ch)) = (u32x2){pack2bf(ac3[0],ac3[1]), pack2bf(ac3[2],ac3[3])}; \
} while (0)

#define DO_K(m, W0, W1, W2) do {                                               \
    MFMA_T(W0, W1, W2)                                                         \
    int jk = ((m) - 6) * 16 + 4 * qg;                                          \
    int cb = jk * 2 + (jk / 24) * 16;                                          \
    int sw = (p & 7) << 4;                                                     \
    *reinterpret_cast<u32x2*>(ksb + (p)      * 256 + (cb ^ sw)) = (u32x2){pack2bf(ac0[0],ac0[1]), pack2bf(ac0[2],ac0[3])}; \
    *reinterpret_cast<u32x2*>(ksb + (16 + p) * 256 + (cb ^ sw)) = (u32x2){pack2bf(ac1[0],ac1[1]), pack2bf(ac1[2],ac1[3])}; \
    *reinterpret_cast<u32x2*>(ksb + (32 + p) * 256 + (cb ^ sw)) = (u32x2){pack2bf(ac2[0],ac2[1]), pack2bf(ac2[2],ac2[3])}; \
    *reinterpret_cast<u32x2*>(ksb + (48 + p) * 256 + (cb ^ sw)) = (u32x2){pack2bf(ac3[0],ac3[1]), pack2bf(ac3[2],ac3[3])}; \
} while (0)

#define STV1(JV, A, T2) do {                                                   \
    int _r0 = (JV);                                                            \
    *reinterpret_cast<unsigned short*>(vtb + (_r0)     * 128 + ((T2) ^ (((_r0)     & 7) << 4))) = cvt_bf(A[0]); \
    *reinterpret_cast<unsigned short*>(vtb + (_r0 + 1) * 128 + ((T2) ^ (((_r0 + 1) & 7) << 4))) = cvt_bf(A[1]); \
    *reinterpret_cast<unsigned short*>(vtb + (_r0 + 2) * 128 + ((T2) ^ (((_r0 + 2) & 7) << 4))) = cvt_bf(A[2]); \
    *reinterpret_cast<unsigned short*>(vtb + (_r0 + 3) * 128 + ((T2) ^ (((_r0 + 3) & 7) << 4))) = cvt_bf(A[3]); \
} while (0)

#define DO_V(m, W0, W1, W2) do {                                               \
    MFMA_T(W0, W1, W2)                                                         \
    int jv = ((m) - 12) * 16 + 4 * qg;                                         \
    STV1(jv, ac0, (p) * 2);                                                    \
    STV1(jv, ac1, (16 + p) * 2);                                               \
    STV1(jv, ac2, (32 + p) * 2);                                               \
    STV1(jv, ac3, (48 + p) * 2);                                               \
} while (0)

#define LOADWP(m, W0, W1, W2) do {                                             \
    const unsigned short* _wp = wpT + ((m) * 16 + p) * 96 + qg * 8;            \
    W0 = *reinterpret_cast<const bf16x8*>(_wp);                                \
    W1 = *reinterpret_cast<const bf16x8*>(_wp + 32);                           \
    W2 = *reinterpret_cast<const bf16x8*>(_wp + 64);                           \
} while (0)

#define PROJ(m, W0, W1, W2) do {                                               \
    f32x4 acc = fzero;                                                         \
    acc = MFMA16(W0, o0, acc);                                                 \
    acc = MFMA16(W1, o1, acc);                                                 \
    acc = MFMA16(W2, o2, acc);                                                 \
    float4 bb = *reinterpret_cast<const float4*>(bproj + (m) * 16 + 4 * qg);   \
    f32x4 r;                                                                   \
    r[0] = acc[0] + bb.x; r[1] = acc[1] + bb.y;                                \
    r[2] = acc[2] + bb.z; r[3] = acc[3] + bb.w;                                \
    *reinterpret_cast<f32x4*>(fbuf + (wv * 16 + p) * 100 + (m) * 16 + 4 * qg) = r; \
} while (0)

// One block per window. 256 threads = 4 waves. Wave wv owns token rows [16wv,16wv+16).
// LDS = 40960 B. All GEMMs operand-swapped (channel-contiguous D rows).
// No fragment array ever crosses a call boundary -> no scratch.
__global__ __launch_bounds__(256, 3)
void winattn_kernel(const float* __restrict__ x,
                    const unsigned short* __restrict__ wsT,
                    const float* __restrict__ bproj,
                    float* __restrict__ out) {
    __shared__ __align__(16) char LDS[40960];
    char* xq  = LDS;              // 12288 B: x -> q -> O (packed-swizzled bf16)
    char* ksb = LDS + 12288;      // 16384 B: k [ktok][hd*32+kk], XOR-swizzled, kk 24..31 zero
    char* vtb = LDS + 28672;      // 12288 B: v^T [ch][tok], XOR-swizzled
    float* fbuf = reinterpret_cast<float*>(LDS + 12288);  // f32 proj out [64][stride 100]

    const int tid = threadIdx.x;
    const int lane = tid & 63;
    const int wv = tid >> 6;
    const int p  = lane & 15;
    const int qg = lane >> 4;

    const int iw  = blockIdx.x;
    const int l_i = iw & 31;
    const int m_i = (iw >> 5) & 15;
    const int n_i = iw >> 9;

    const f32x4 fzero = {0.f, 0.f, 0.f, 0.f};

    // ---------- phase 0: prefetch this wave's first W-tile ----------
    bf16x8 wA0, wA1, wA2, wB0, wB1, wB2;
    const int tb0 = (wv < 2) ? wv * 5 : 10 + (wv - 2) * 4;
    LOADW(tb0, wA0, wA1, wA2);

    // ---------- phase 1: stage x window -> LDS (bf16, packed layout) ----------
    #pragma unroll
    for (int it = 0; it < 6; ++it) {
        int slot = tid + it * 256;            // 64 tokens * 24 float4 slots
        int t = slot / 24, cq = slot % 24;
        int td = t >> 4, th = (t >> 2) & 3, tw = t & 3;
        int off = (((n_i * 4 + td) * 64 + (m_i * 4 + th)) * 128 + (l_i * 4 + tw)) * 96 + cq * 4;
        float4 v4 = *reinterpret_cast<const float4*>(x + off);
        u16x4 h;
        h[0] = cvt_bf(v4.x); h[1] = cvt_bf(v4.y); h[2] = cvt_bf(v4.z); h[3] = cvt_bf(v4.w);
        *reinterpret_cast<u16x4*>(xq + xq_addr(t, cq * 4)) = h;
    }
    // zero k head-pads (kk 24..31 per head, swizzled addr)
    {
        int t = tid >> 2, hd = tid & 3;
        bf16x8 z = {0, 0, 0, 0, 0, 0, 0, 0};
        int cb = hd * 64 + 48;
        *reinterpret_cast<bf16x8*>(ksb + t * 256 + (cb ^ ((t & 7) << 4))) = z;
    }
    __syncthreads();

    // ---------- phase 2: QKV GEMM (swapped)  qkv^T[288][64] = wq^T[288][96] @ x^T[96][64] ----------
    bf16x8 a00, a01, a02, a10, a11, a12, a20, a21, a22, a30, a31, a32;
    {
        const char* xb = xq;
        a00 = *reinterpret_cast<const bf16x8*>(xb + xq_addr(p,      qg * 8));
        a01 = *reinterpret_cast<const bf16x8*>(xb + xq_addr(p,      32 + qg * 8));
        a02 = *reinterpret_cast<const bf16x8*>(xb + xq_addr(p,      64 + qg * 8));
        a10 = *reinterpret_cast<const bf16x8*>(xb + xq_addr(16 + p, qg * 8));
        a11 = *reinterpret_cast<const bf16x8*>(xb + xq_addr(16 + p, 32 + qg * 8));
        a12 = *reinterpret_cast<const bf16x8*>(xb + xq_addr(16 + p, 64 + qg * 8));
        a20 = *reinterpret_cast<const bf16x8*>(xb + xq_addr(32 + p, qg * 8));
        a21 = *reinterpret_cast<const bf16x8*>(xb + xq_addr(32 + p, 32 + qg * 8));
        a22 = *reinterpret_cast<const bf16x8*>(xb + xq_addr(32 + p, 64 + qg * 8));
        a30 = *reinterpret_cast<const bf16x8*>(xb + xq_addr(48 + p, qg * 8));
        a31 = *reinterpret_cast<const bf16x8*>(xb + xq_addr(48 + p, 32 + qg * 8));
        a32 = *reinterpret_cast<const bf16x8*>(xb + xq_addr(48 + p, 64 + qg * 8));
    }
    __syncthreads();   // x fully register-hoisted; q may now overwrite xq

    if (wv == 0) {          // tiles 0-4: all q
        LOADW(1, wB0, wB1, wB2); DO_Q(0, wA0, wA1, wA2);
        LOADW(2, wA0, wA1, wA2); DO_Q(1, wB0, wB1, wB2);
        LOADW(3, wB0, wB1, wB2); DO_Q(2, wA0, wA1, wA2);
        LOADW(4, wA0, wA1, wA2); DO_Q(3, wB0, wB1, wB2);
        DO_Q(4, wA0, wA1, wA2);
    } else if (wv == 1) {   // tiles 5-9: q, then k
        LOADW(6, wB0, wB1, wB2); DO_Q(5, wA0, wA1, wA2);
        LOADW(7, wA0, wA1, wA2); DO_K(6, wB0, wB1, wB2);
        LOADW(8, wB0, wB1, wB2); DO_K(7, wA0, wA1, wA2);
        LOADW(9, wA0, wA1, wA2); DO_K(8, wB0, wB1, wB2);
        DO_K(9, wA0, wA1, wA2);
    } else if (wv == 2) {   // tiles 10-13: k, k, v, v
        LOADW(11, wB0, wB1, wB2); DO_K(10, wA0, wA1, wA2);
        LOADW(12, wA0, wA1, wA2); DO_K(11, wB0, wB1, wB2);
        LOADW(13, wB0, wB1, wB2); DO_V(12, wA0, wA1, wA2);
        DO_V(13, wB0, wB1, wB2);
    } else {                // tiles 14-17: all v
        LOADW(15, wB0, wB1, wB2); DO_V(14, wA0, wA1, wA2);
        LOADW(16, wA0, wA1, wA2); DO_V(15, wB0, wB1, wB2);
        LOADW(17, wB0, wB1, wB2); DO_V(16, wA0, wA1, wA2);
        DO_V(17, wB0, wB1, wB2);
    }
    __syncthreads();

    // ---------- phase 3: attention, swapped QK^T -> register softmax -> swapped PV ----------
    #pragma unroll 1
    for (int hd = 0; hd < 4; ++hd) {
        // S^T = mfma(K, Q): D[col=q-token(p), row=k-token(qg*4+rg)+16nt]
        bf16x8 aqh = *reinterpret_cast<const bf16x8*>(xq + xq_addr(wv * 16 + p, hd * 24 + qg * 8));
        f32x4 sacc[4];
        #pragma unroll
        for (int nt = 0; nt < 4; ++nt) {
            int t = nt * 16 + p;
            bf16x8 ak = *reinterpret_cast<const bf16x8*>(ksb + t * 256 + ((hd * 64 + qg * 16) ^ ((t & 7) << 4)));
            sacc[nt] = MFMA16(ak, aqh, fzero);
        }
        // lane (p,qg) holds S[k = 16nt+4qg+rg][q = wv*16+p] (already *scale*log2e)
        float mm = sacc[0][0];
        #pragma unroll
        for (int nt = 0; nt < 4; ++nt)
            #pragma unroll
            for (int rg = 0; rg < 4; ++rg)
                mm = fmaxf(mm, sacc[nt][rg]);
        mm = fmaxf(mm, __shfl_xor(mm, 16));
        mm = fmaxf(mm, __shfl_xor(mm, 32));
        float pw[4][4];
        float sum = 0.f;
        #pragma unroll
        for (int nt = 0; nt < 4; ++nt)
            #pragma unroll
            for (int rg = 0; rg < 4; ++rg) {
                float e = exp2f(sacc[nt][rg] - mm);
                pw[nt][rg] = e;
                sum += e;
            }
        sum += __shfl_xor(sum, 16);
        sum += __shfl_xor(sum, 32);
        float inv = 1.0f / sum;
        unsigned pk[4][2];
        #pragma unroll
        for (int nt = 0; nt < 4; ++nt) {
            pk[nt][0] = pack2bf(pw[nt][0] * inv, pw[nt][1] * inv);
            pk[nt][1] = pack2bf(pw[nt][2] * inv, pw[nt][3] * inv);
        }
        // redistribute so lane (p,qg) holds P[qtok=p][ktok = kt*32 + qg*8 + j]
        u32x4 pa0, pa1;
        #pragma unroll
        for (int d = 0; d < 4; ++d) {
            int src = ((qg & 1) * 2 + (d >> 1)) * 16 + p;
            int lo0 = __shfl((int)pk[0][d & 1], src);
            int hi0 = __shfl((int)pk[1][d & 1], src);
            int lo1 = __shfl((int)pk[2][d & 1], src);
            int hi1 = __shfl((int)pk[3][d & 1], src);
            pa0[d] = (qg < 2) ? (unsigned)lo0 : (unsigned)hi0;
            pa1[d] = (qg < 2) ? (unsigned)lo1 : (unsigned)hi1;
        }
        bf16x8 pA0 = __builtin_bit_cast(bf16x8, pa0);
        bf16x8 pA1 = __builtin_bit_cast(bf16x8, pa1);
        // O^T = mfma(V^T, P^T)
        f32x4 oacc[2] = {fzero, fzero};
        #pragma unroll
        for (int n2 = 0; n2 < 2; ++n2) {
            int vr = hd * 24 + n2 * 16 + p;
            vr = vr > 95 ? 95 : vr;           // clamped garbage rows land in discarded D rows
            int rb = vr * 128, sw = (vr & 7) << 4;
            bf16x8 av0 = *reinterpret_cast<const bf16x8*>(vtb + rb + ((qg * 16) ^ sw));
            bf16x8 av1 = *reinterpret_cast<const bf16x8*>(vtb + rb + ((64 + qg * 16) ^ sw));
            oacc[n2] = MFMA16(av0, pA0, oacc[n2]);
            oacc[n2] = MFMA16(av1, pA1, oacc[n2]);
        }
        // lane holds O[tok = wv*16+p][ch = hd*24 + n2*16 + 4qg + rg] -> b64 stores into xq
        {
            u32x2 w0 = { pack2bf(oacc[0][0], oacc[0][1]), pack2bf(oacc[0][2], oacc[0][3]) };
            *reinterpret_cast<u32x2*>(xq + xq_addr(wv * 16 + p, hd * 24 + 4 * qg)) = w0;
            if (qg < 2) {
                u32x2 w1 = { pack2bf(oacc[1][0], oacc[1][1]), pack2bf(oacc[1][2], oacc[1][3]) };
                *reinterpret_cast<u32x2*>(xq + xq_addr(wv * 16 + p, hd * 24 + 16 + 4 * qg)) = w1;
            }
        }
    }

    // ---------- phase 4: proj (swapped) + bias -> f32 LDS (own rows only) ----------
    bf16x8 o0, o1, o2;
    o0 = *reinterpret_cast<const bf16x8*>(xq + xq_addr(wv * 16 + p, qg * 8));
    o1 = *reinterpret_cast<const bf16x8*>(xq + xq_addr(wv * 16 + p, 32 + qg * 8));
    o2 = *reinterpret_cast<const bf16x8*>(xq + xq_addr(wv * 16 + p, 64 + qg * 8));
    __syncthreads();   // all waves done with ksb/vtb before fbuf overlays them

    const unsigned short* wpT = wsT + WQT_ELEMS;
    LOADWP(0, wA0, wA1, wA2);
    LOADWP(1, wB0, wB1, wB2); PROJ(0, wA0, wA1, wA2);
    LOADWP(2, wA0, wA1, wA2); PROJ(1, wB0, wB1, wB2);
    LOADWP(3, wB0, wB1, wB2); PROJ(2, wA0, wA1, wA2);
    LOADWP(4, wA0, wA1, wA2); PROJ(3, wB0, wB1, wB2);
    LOADWP(5, wB0, wB1, wB2); PROJ(4, wA0, wA1, wA2);
    PROJ(5, wB0, wB1, wB2);
    __syncthreads();

    // ---------- phase 5: cooperative fully-coalesced f32 store ----------
    #pragma unroll
    for (int it = 0; it < 6; ++it) {
        int slot = tid + it * 256;
        int t = slot / 24, cq = slot % 24;
        int td = t >> 4, th = (t >> 2) & 3, tw = t & 3;
        int off = (((n_i * 4 + td) * 64 + (m_i * 4 + th)) * 128 + (l_i * 4 + tw)) * 96 + cq * 4;
        float4 v4 = *reinterpret_cast<const float4*>(fbuf + t * 100 + cq * 4);
        *reinterpret_cast<float4*>(out + off) = v4;
    }
}

extern "C" void kernel_launch(void* const* d_in, const int* in_sizes, int n_in,
                              void* d_out, int out_size, void* d_ws, size_t ws_size,
                              hipStream_t stream) {
    const float* x     = (const float*)d_in[0];
    const float* wqkv  = (const float*)d_in[1];
    const float* wproj = (const float*)d_in[2];
    const float* bproj = (const float*)d_in[3];
    float* out = (float*)d_out;
    unsigned short* wsT = (unsigned short*)d_ws;

    wconv_kernel<<<dim3((WQT_ELEMS + WPT_ELEMS) / 256), dim3(256), 0, stream>>>(wqkv, wproj, wsT);
    winattn_kernel<<<dim3(4096), dim3(256), 0, stream>>>(x, wsT, bproj, out);
}